// Round 4
// baseline (192.749 us; speedup 1.0000x reference)
//
#include <hip/hip_runtime.h>
#include <hip/hip_bf16.h>

#define VOCAB 100000
#define EMBED 64
#define SENT  20
#define MEM   50
#define BATCH 32
#define HOPS  3

__device__ __forceinline__ float bfr(unsigned short x) {
    union { unsigned int u; float f; } cv;
    cv.u = ((unsigned int)x) << 16;
    return cv.f;
}

// Runtime dtype probe: enc row 19 (last) is exactly 1.0 everywhere.
// bf16 storage: dword 639 packs elements 1278,1279 = (1.0bf,1.0bf) = 0x3F803F80.
// f32 storage: dword 639 = bits of enc[9][63] ~= 0.9508.
__device__ __forceinline__ bool is_bf16(const void* enc) {
    return ((const unsigned int*)enc)[639] == 0x3F803F80u;
}

__device__ __forceinline__ float loadT(const void* p, size_t idx, bool bf) {
    return bf ? bfr(((const unsigned short*)p)[idx]) : ((const float*)p)[idx];
}

__device__ __forceinline__ float wave_sum(float d) {
#pragma unroll
    for (int off = 32; off > 0; off >>= 1) d += __shfl_xor(d, off, 64);
    return d;
}

// One block per batch. 1024 threads = 16 waves; wave w handles memories
// mm = w, w+16, w+32 (w+48 for w<2). All per-batch state in LDS; u replicated
// per-wave in registers (lane e holds u[e]). No inter-block communication.
__global__ __launch_bounds__(1024) void k_recur(
    const int* __restrict__ stories,   // [32,50,20]
    const int* __restrict__ queries,   // [32,20]
    const void* __restrict__ A,        // [V,64]
    const void* __restrict__ C,        // [3,V,64]
    const void* __restrict__ enc,      // [20,64]
    float* __restrict__ u3g)           // out: [32,64]
{
    const bool bf = is_bf16(enc);
    const int b    = blockIdx.x;
    const int tid  = threadIdx.x;
    const int e    = tid & 63;
    const int widx = tid >> 6;

    __shared__ float cls[MEM][EMBED];  // c-vectors of current hop (12.8 KB)
    __shared__ float dls[MEM];         // dotted of current hop

    const size_t VE = (size_t)VOCAB * EMBED;

    float encr[SENT];
#pragma unroll
    for (int s = 0; s < SENT; ++s) encr[s] = loadT(enc, s * EMBED + e, bf);

    // ---- u0, computed redundantly by every wave (A rows L1-broadcast) ----
    float u_e = 0.f;
    {
        int wq = (e < SENT) ? queries[b * SENT + e] : 0;
#pragma unroll
        for (int s = 0; s < SENT; ++s) {
            int w = __shfl(wq, s, 64);
            u_e += loadT(A, (size_t)w * EMBED + e, bf) * encr[s];
        }
    }

    for (int hop = 0; hop < HOPS; ++hop) {
        const void* Tin   = (hop == 0) ? A : C;
        const size_t toff = (hop == 2) ? VE : 0;      // hop0:A+0, hop1:C+0, hop2:C+VE
        const size_t coff = (size_t)hop * VE;

        // gather m,c for this wave's memories; write c + dotted to LDS
        for (int mm = widx; mm < MEM; mm += 16) {
            int wst = (e < SENT) ? stories[(b * MEM + mm) * SENT + e] : 0;
            float macc = 0.f, cacc = 0.f;
#pragma unroll
            for (int s = 0; s < SENT; ++s) {
                int w = __shfl(wst, s, 64);
                size_t ro = (size_t)w * EMBED + e;
                macc += loadT(Tin, toff + ro, bf) * encr[s];
                cacc += loadT(C, coff + ro, bf) * encr[s];
            }
            cls[mm][e] = cacc;
            float d = wave_sum(macc * u_e);
            if (e == 0) dls[mm] = d;
        }
        __syncthreads();

        // softmax over 50 + weighted sum, redundantly per wave
        float x = (e < MEM) ? dls[e] : -3.4e38f;
        float mx = x;
#pragma unroll
        for (int off = 32; off > 0; off >>= 1) mx = fmaxf(mx, __shfl_xor(mx, off, 64));
        float ex = (e < MEM) ? __expf(x - mx) : 0.f;
        float sm = wave_sum(ex);
        float p = ex / sm;
        float o = 0.f;
#pragma unroll
        for (int mm = 0; mm < MEM; ++mm)
            o += __shfl(p, mm, 64) * cls[mm][e];
        u_e += o;
        __syncthreads();   // all waves done reading cls/dls before next hop rewrites
    }

    if (widx == 0) u3g[b * EMBED + e] = u_e;
}

// out[b*V+v] = sum_e u3[b][e] * C[2][v][e]   (identical to the R2-passing k_out)
__global__ __launch_bounds__(256) void k_out(const float* __restrict__ u,
                                             const void* __restrict__ Cbase,
                                             const void* __restrict__ enc,
                                             void* __restrict__ out)
{
    bool bf = is_bf16(enc);
    const size_t c2_off = (size_t)2 * VOCAB * EMBED;
    __shared__ __align__(16) float su[BATCH * EMBED];
    for (int i = threadIdx.x; i < BATCH * EMBED; i += 256) su[i] = u[i];
    __syncthreads();
    int v = blockIdx.x * 256 + threadIdx.x;
    if (v >= VOCAB) return;

    float row[EMBED];
    if (bf) {
        const uint4* rp = (const uint4*)((const unsigned short*)Cbase + c2_off + (size_t)v * EMBED);
#pragma unroll
        for (int i = 0; i < 8; ++i) {
            uint4 r = rp[i];
            row[i*8 + 0] = bfr((unsigned short)(r.x & 0xffff));
            row[i*8 + 1] = bfr((unsigned short)(r.x >> 16));
            row[i*8 + 2] = bfr((unsigned short)(r.y & 0xffff));
            row[i*8 + 3] = bfr((unsigned short)(r.y >> 16));
            row[i*8 + 4] = bfr((unsigned short)(r.z & 0xffff));
            row[i*8 + 5] = bfr((unsigned short)(r.z >> 16));
            row[i*8 + 6] = bfr((unsigned short)(r.w & 0xffff));
            row[i*8 + 7] = bfr((unsigned short)(r.w >> 16));
        }
    } else {
        const float4* rp = (const float4*)((const float*)Cbase + c2_off + (size_t)v * EMBED);
#pragma unroll
        for (int i = 0; i < 16; ++i) {
            float4 r = rp[i];
            row[i*4 + 0] = r.x; row[i*4 + 1] = r.y;
            row[i*4 + 2] = r.z; row[i*4 + 3] = r.w;
        }
    }

    float res[BATCH];
#pragma unroll
    for (int bb = 0; bb < BATCH; ++bb) {
        const float4* sp = (const float4*)(su + bb * EMBED);
        float acc = 0.f;
#pragma unroll
        for (int e4 = 0; e4 < 16; ++e4) {
            float4 us = sp[e4];
            acc += row[e4*4+0]*us.x + row[e4*4+1]*us.y
                 + row[e4*4+2]*us.z + row[e4*4+3]*us.w;
        }
        res[bb] = acc;
    }

    if (bf) {
        unsigned short* ob = (unsigned short*)out;
#pragma unroll
        for (int bb = 0; bb < BATCH; ++bb) {
            __hip_bfloat16 h = __float2bfloat16(res[bb]);
            ob[(size_t)bb * VOCAB + v] = *(unsigned short*)&h;
        }
    } else {
        float* of = (float*)out;
#pragma unroll
        for (int bb = 0; bb < BATCH; ++bb)
            of[(size_t)bb * VOCAB + v] = res[bb];
    }
}

extern "C" void kernel_launch(void* const* d_in, const int* in_sizes, int n_in,
                              void* d_out, int out_size, void* d_ws, size_t ws_size,
                              hipStream_t stream)
{
    const int*  stories = (const int*)d_in[0];
    const int*  queries = (const int*)d_in[1];
    const void* A       = d_in[2];
    const void* C       = d_in[3];
    const void* enc     = d_in[4];
    float*      u3g     = (float*)d_ws;   // 32*64 floats

    k_recur<<<BATCH, 1024, 0, stream>>>(stories, queries, A, C, enc, u3g);
    k_out<<<(VOCAB + 255) / 256, 256, 0, stream>>>(u3g, C, enc, d_out);
}

// Round 5
// 183.365 us; speedup vs baseline: 1.0512x; 1.0512x over previous
//
#include <hip/hip_runtime.h>
#include <hip/hip_bf16.h>

#define VOCAB 100000
#define EMBED 64
#define SENT  20
#define MEM   50
#define BATCH 32
#define HOPS  3

#define NSLOT (HOPS * BATCH * MEM)   // 4800 gather slots

__device__ __forceinline__ float bfr(unsigned short x) {
    union { unsigned int u; float f; } cv;
    cv.u = ((unsigned int)x) << 16;
    return cv.f;
}

// Runtime dtype probe: enc row 19 (last) is exactly 1.0 everywhere.
// bf16 storage: dword 639 packs elements 1278,1279 = (1.0bf,1.0bf) = 0x3F803F80.
// f32 storage: dword 639 = bits of enc[9][63] ~= 0.9508.
__device__ __forceinline__ bool is_bf16(const void* enc) {
    return ((const unsigned int*)enc)[639] == 0x3F803F80u;
}

__device__ __forceinline__ float loadT(const void* p, size_t idx, bool bf) {
    return bf ? bfr(((const unsigned short*)p)[idx]) : ((const float*)p)[idx];
}

__device__ __forceinline__ float wave_sum(float d) {
#pragma unroll
    for (int off = 32; off > 0; off >>= 1) d += __shfl_xor(d, off, 64);
    return d;
}

// Full-width u-independent gather: wave gw<4800 handles slot (hop, bm):
//   m_ws[gw][e] = sum_s Tin[w_s][e]*enc[s][e]; c_ws[gw][e] = sum_s C[hop][w_s][e]*enc[s][e]
// waves 4800..4831 compute u0 for batch gw-4800.
__global__ __launch_bounds__(256) void k_gather(
    const int* __restrict__ stories,   // [32,50,20]
    const int* __restrict__ queries,   // [32,20]
    const void* __restrict__ A,        // [V,64]
    const void* __restrict__ C,        // [3,V,64]
    const void* __restrict__ enc,      // [20,64]
    float* __restrict__ m_ws,          // [4800,64]
    float* __restrict__ c_ws,          // [4800,64]
    float* __restrict__ u0g)           // [32,64]
{
    const bool bf = is_bf16(enc);
    const int tid  = threadIdx.x;
    const int e    = tid & 63;
    const int gw   = blockIdx.x * 4 + (tid >> 6);
    const size_t VE = (size_t)VOCAB * EMBED;

    float encr[SENT];
#pragma unroll
    for (int s = 0; s < SENT; ++s) encr[s] = loadT(enc, s * EMBED + e, bf);

    if (gw < NSLOT) {
        const int hop = gw / (BATCH * MEM);
        const int bm  = gw % (BATCH * MEM);
        const void* Tin   = (hop == 0) ? A : C;
        const size_t toff = (hop == 2) ? VE : 0;   // hop0:A, hop1:C0, hop2:C1
        const size_t coff = (size_t)hop * VE;

        int wst = (e < SENT) ? stories[bm * SENT + e] : 0;
        float macc = 0.f, cacc = 0.f;
#pragma unroll
        for (int s = 0; s < SENT; ++s) {
            int w = __shfl(wst, s, 64);
            size_t ro = (size_t)w * EMBED + e;
            macc += loadT(Tin, toff + ro, bf) * encr[s];
            cacc += loadT(C, coff + ro, bf) * encr[s];
        }
        m_ws[gw * EMBED + e] = macc;
        c_ws[gw * EMBED + e] = cacc;
    } else if (gw < NSLOT + BATCH) {
        const int b = gw - NSLOT;
        int wq = (e < SENT) ? queries[b * SENT + e] : 0;
        float u = 0.f;
#pragma unroll
        for (int s = 0; s < SENT; ++s) {
            int w = __shfl(wq, s, 64);
            u += loadT(A, (size_t)w * EMBED + e, bf) * encr[s];
        }
        u0g[b * EMBED + e] = u;
    }
}

// Per-batch recurrence: one wave per batch, data L2-hot from k_gather.
__global__ __launch_bounds__(64) void k_recur2(
    const float* __restrict__ m_ws,
    const float* __restrict__ c_ws,
    const float* __restrict__ u0g,
    float* __restrict__ u3g)
{
    const int b = blockIdx.x;
    const int e = threadIdx.x;

    float u = u0g[b * EMBED + e];

    for (int hop = 0; hop < HOPS; ++hop) {
        const size_t base = ((size_t)hop * BATCH * MEM + b * MEM) * EMBED;

        // dots: prefetch 10 m-vectors at a time to keep loads independent
        float dval = -3.4e38f;
#pragma unroll
        for (int g = 0; g < MEM; g += 10) {
            float mv[10];
#pragma unroll
            for (int k = 0; k < 10; ++k)
                mv[k] = m_ws[base + (g + k) * EMBED + e];
#pragma unroll
            for (int k = 0; k < 10; ++k) {
                float d = wave_sum(mv[k] * u);
                if (e == g + k) dval = d;
            }
        }

        // softmax over lanes 0..49
        float mx = dval;
#pragma unroll
        for (int off = 32; off > 0; off >>= 1) mx = fmaxf(mx, __shfl_xor(mx, off, 64));
        float ex = (e < MEM) ? __expf(dval - mx) : 0.f;
        float sm = wave_sum(ex);
        float p = ex / sm;

        // o_e = sum_mm p_mm * c[mm][e]
        float o = 0.f;
#pragma unroll
        for (int mm = 0; mm < MEM; ++mm)
            o += __shfl(p, mm, 64) * c_ws[base + mm * EMBED + e];
        u += o;
    }
    u3g[b * EMBED + e] = u;
}

// out[b*V+v] = sum_e u3[b][e] * C[2][v][e]   (R2-proven)
__global__ __launch_bounds__(256) void k_out(const float* __restrict__ u,
                                             const void* __restrict__ Cbase,
                                             const void* __restrict__ enc,
                                             void* __restrict__ out)
{
    bool bf = is_bf16(enc);
    const size_t c2_off = (size_t)2 * VOCAB * EMBED;
    __shared__ __align__(16) float su[BATCH * EMBED];
    for (int i = threadIdx.x; i < BATCH * EMBED; i += 256) su[i] = u[i];
    __syncthreads();
    int v = blockIdx.x * 256 + threadIdx.x;
    if (v >= VOCAB) return;

    float row[EMBED];
    if (bf) {
        const uint4* rp = (const uint4*)((const unsigned short*)Cbase + c2_off + (size_t)v * EMBED);
#pragma unroll
        for (int i = 0; i < 8; ++i) {
            uint4 r = rp[i];
            row[i*8 + 0] = bfr((unsigned short)(r.x & 0xffff));
            row[i*8 + 1] = bfr((unsigned short)(r.x >> 16));
            row[i*8 + 2] = bfr((unsigned short)(r.y & 0xffff));
            row[i*8 + 3] = bfr((unsigned short)(r.y >> 16));
            row[i*8 + 4] = bfr((unsigned short)(r.z & 0xffff));
            row[i*8 + 5] = bfr((unsigned short)(r.z >> 16));
            row[i*8 + 6] = bfr((unsigned short)(r.w & 0xffff));
            row[i*8 + 7] = bfr((unsigned short)(r.w >> 16));
        }
    } else {
        const float4* rp = (const float4*)((const float*)Cbase + c2_off + (size_t)v * EMBED);
#pragma unroll
        for (int i = 0; i < 16; ++i) {
            float4 r = rp[i];
            row[i*4 + 0] = r.x; row[i*4 + 1] = r.y;
            row[i*4 + 2] = r.z; row[i*4 + 3] = r.w;
        }
    }

    float res[BATCH];
#pragma unroll
    for (int bb = 0; bb < BATCH; ++bb) {
        const float4* sp = (const float4*)(su + bb * EMBED);
        float acc = 0.f;
#pragma unroll
        for (int e4 = 0; e4 < 16; ++e4) {
            float4 us = sp[e4];
            acc += row[e4*4+0]*us.x + row[e4*4+1]*us.y
                 + row[e4*4+2]*us.z + row[e4*4+3]*us.w;
        }
        res[bb] = acc;
    }

    if (bf) {
        unsigned short* ob = (unsigned short*)out;
#pragma unroll
        for (int bb = 0; bb < BATCH; ++bb) {
            __hip_bfloat16 h = __float2bfloat16(res[bb]);
            ob[(size_t)bb * VOCAB + v] = *(unsigned short*)&h;
        }
    } else {
        float* of = (float*)out;
#pragma unroll
        for (int bb = 0; bb < BATCH; ++bb)
            of[(size_t)bb * VOCAB + v] = res[bb];
    }
}

extern "C" void kernel_launch(void* const* d_in, const int* in_sizes, int n_in,
                              void* d_out, int out_size, void* d_ws, size_t ws_size,
                              hipStream_t stream)
{
    const int*  stories = (const int*)d_in[0];
    const int*  queries = (const int*)d_in[1];
    const void* A       = d_in[2];
    const void* C       = d_in[3];
    const void* enc     = d_in[4];

    float* m_ws = (float*)d_ws;                 // [4800,64]
    float* c_ws = m_ws + NSLOT * EMBED;         // [4800,64]
    float* u0g  = c_ws + NSLOT * EMBED;         // [32,64]
    float* u3g  = u0g + BATCH * EMBED;          // [32,64]

    const int nwaves  = NSLOT + BATCH;                 // 4832
    const int nblocks = (nwaves + 3) / 4;              // 1208 blocks x 256

    k_gather<<<nblocks, 256, 0, stream>>>(stories, queries, A, C, enc, m_ws, c_ws, u0g);
    k_recur2<<<BATCH, 64, 0, stream>>>(m_ws, c_ws, u0g, u3g);
    k_out<<<(VOCAB + 255) / 256, 256, 0, stream>>>(u3g, C, enc, d_out);
}

// Round 6
// 159.437 us; speedup vs baseline: 1.2089x; 1.1501x over previous
//
#include <hip/hip_runtime.h>
#include <hip/hip_bf16.h>

#define VOCAB 100000
#define EMBED 64
#define SENT  20
#define MEM   50
#define BATCH 32
#define HOPS  3

// 4 gather sets: t=0 -> A (m for hop0); t=1..3 -> C[t-1] (c for hop t-1, m for hop t).
// Exploits m_h == c_{h-1} (same table, same words, same encoding).
#define NSET  4
#define NSLOT (NSET * BATCH * MEM)   // 6400

__device__ __forceinline__ float bfr(unsigned short x) {
    union { unsigned int u; float f; } cv;
    cv.u = ((unsigned int)x) << 16;
    return cv.f;
}

// Runtime dtype probe: enc row 19 (last) is exactly 1.0 everywhere.
// bf16 storage: dword 639 packs elements 1278,1279 = (1.0bf,1.0bf) = 0x3F803F80.
__device__ __forceinline__ bool is_bf16(const void* enc) {
    return ((const unsigned int*)enc)[639] == 0x3F803F80u;
}

__device__ __forceinline__ float loadT(const void* p, size_t idx, bool bf) {
    return bf ? bfr(((const unsigned short*)p)[idx]) : ((const float*)p)[idx];
}

__device__ __forceinline__ float wave_sum(float d) {
#pragma unroll
    for (int off = 32; off > 0; off >>= 1) d += __shfl_xor(d, off, 64);
    return d;
}

// Wave gw < 6400 computes one (t, bm) position-encoded sentence vector:
//   mc_ws[gw][e] = sum_s T_t[w_s][e] * enc[s][e]
// Waves 6400..6431 compute u0 for batch gw-6400.
__global__ __launch_bounds__(256) void k_gather(
    const int* __restrict__ stories,   // [32,50,20]
    const int* __restrict__ queries,   // [32,20]
    const void* __restrict__ A,        // [V,64]
    const void* __restrict__ C,        // [3,V,64]
    const void* __restrict__ enc,      // [20,64]
    float* __restrict__ mc_ws,         // [6400,64]
    float* __restrict__ u0g)           // [32,64]
{
    const bool bf = is_bf16(enc);
    const int tid = threadIdx.x;
    const int e   = tid & 63;
    const int gw  = blockIdx.x * 4 + (tid >> 6);
    const size_t VE = (size_t)VOCAB * EMBED;

    float encr[SENT];
#pragma unroll
    for (int s = 0; s < SENT; ++s) encr[s] = loadT(enc, s * EMBED + e, bf);

    if (gw < NSLOT) {
        const int t  = gw / (BATCH * MEM);
        const int bm = gw % (BATCH * MEM);
        const void* T   = (t == 0) ? A : C;
        const size_t to = (t == 0) ? 0 : (size_t)(t - 1) * VE;

        int wst = (e < SENT) ? stories[bm * SENT + e] : 0;
        float acc = 0.f;
#pragma unroll
        for (int s = 0; s < SENT; ++s) {
            int w = __shfl(wst, s, 64);
            acc += loadT(T, to + (size_t)w * EMBED + e, bf) * encr[s];
        }
        mc_ws[gw * EMBED + e] = acc;
    } else if (gw < NSLOT + BATCH) {
        const int b = gw - NSLOT;
        int wq = (e < SENT) ? queries[b * SENT + e] : 0;
        float u = 0.f;
#pragma unroll
        for (int s = 0; s < SENT; ++s) {
            int w = __shfl(wq, s, 64);
            u += loadT(A, (size_t)w * EMBED + e, bf) * encr[s];
        }
        u0g[b * EMBED + e] = u;
    }
}

// One block (256 thr = 4 waves) per batch. All 4 sets preloaded to LDS
// (51 KB, stride-65 pad: both row and column views <=2-way = conflict-free).
// 3-hop recurrence entirely from LDS.
__global__ __launch_bounds__(256) void k_recur2(
    const float* __restrict__ mc_ws,   // [4,1600,64] = [t][b*50+mm][e]
    const float* __restrict__ u0g,
    float* __restrict__ u3g)
{
    const int b    = blockIdx.x;
    const int tid  = threadIdx.x;
    const int lane = tid & 63;
    const int widx = tid >> 6;

    __shared__ float mc[NSET][MEM][65];   // 52 KB
    __shared__ float uls[EMBED];
    __shared__ float ols[4][EMBED];

    // cooperative float4 load: 4 sets x 50 rows x 16 float4 = 3200 loads
    for (int idx = tid; idx < NSET * MEM * 16; idx += 256) {
        int t  = idx / (MEM * 16);
        int r  = idx % (MEM * 16);
        int mm = r >> 4;
        int e4 = r & 15;
        const float4 v = *(const float4*)(mc_ws +
            (((size_t)t * BATCH * MEM) + (size_t)b * MEM + mm) * EMBED + e4 * 4);
        mc[t][mm][e4 * 4 + 0] = v.x;
        mc[t][mm][e4 * 4 + 1] = v.y;
        mc[t][mm][e4 * 4 + 2] = v.z;
        mc[t][mm][e4 * 4 + 3] = v.w;
    }
    if (tid < EMBED) uls[tid] = u0g[b * EMBED + tid];
    __syncthreads();

    for (int hop = 0; hop < HOPS; ++hop) {
        // dot: lane mm computes <m[mm], u> from LDS (all waves redundantly)
        float d = 0.f;
        if (lane < MEM) {
#pragma unroll
            for (int e = 0; e < EMBED; ++e)
                d += mc[hop][lane][e] * uls[e];
        }
        // softmax over lanes 0..49 (in-lane, per wave)
        float x = (lane < MEM) ? d : -3.4e38f;
        float mx = x;
#pragma unroll
        for (int off = 32; off > 0; off >>= 1) mx = fmaxf(mx, __shfl_xor(mx, off, 64));
        float ex = (lane < MEM) ? __expf(x - mx) : 0.f;
        float sm = wave_sum(ex);
        float p = ex / sm;

        // weighted sum: wave w covers mm = 13w .. 13w+12 (w3: 39..49)
        float o = 0.f;
#pragma unroll
        for (int k = 0; k < 13; ++k) {
            int mm = widx * 13 + k;
            if (mm < MEM)
                o += __shfl(p, mm, 64) * mc[hop + 1][mm][lane];
        }
        ols[widx][lane] = o;
        __syncthreads();
        if (tid < EMBED)
            uls[tid] += ols[0][tid] + ols[1][tid] + ols[2][tid] + ols[3][tid];
        __syncthreads();
    }

    if (tid < EMBED) u3g[b * EMBED + tid] = uls[tid];
}

// out[b*V+v] = sum_e u3[b][e] * C[2][v][e]   (R2-proven)
__global__ __launch_bounds__(256) void k_out(const float* __restrict__ u,
                                             const void* __restrict__ Cbase,
                                             const void* __restrict__ enc,
                                             void* __restrict__ out)
{
    bool bf = is_bf16(enc);
    const size_t c2_off = (size_t)2 * VOCAB * EMBED;
    __shared__ __align__(16) float su[BATCH * EMBED];
    for (int i = threadIdx.x; i < BATCH * EMBED; i += 256) su[i] = u[i];
    __syncthreads();
    int v = blockIdx.x * 256 + threadIdx.x;
    if (v >= VOCAB) return;

    float row[EMBED];
    if (bf) {
        const uint4* rp = (const uint4*)((const unsigned short*)Cbase + c2_off + (size_t)v * EMBED);
#pragma unroll
        for (int i = 0; i < 8; ++i) {
            uint4 r = rp[i];
            row[i*8 + 0] = bfr((unsigned short)(r.x & 0xffff));
            row[i*8 + 1] = bfr((unsigned short)(r.x >> 16));
            row[i*8 + 2] = bfr((unsigned short)(r.y & 0xffff));
            row[i*8 + 3] = bfr((unsigned short)(r.y >> 16));
            row[i*8 + 4] = bfr((unsigned short)(r.z & 0xffff));
            row[i*8 + 5] = bfr((unsigned short)(r.z >> 16));
            row[i*8 + 6] = bfr((unsigned short)(r.w & 0xffff));
            row[i*8 + 7] = bfr((unsigned short)(r.w >> 16));
        }
    } else {
        const float4* rp = (const float4*)((const float*)Cbase + c2_off + (size_t)v * EMBED);
#pragma unroll
        for (int i = 0; i < 16; ++i) {
            float4 r = rp[i];
            row[i*4 + 0] = r.x; row[i*4 + 1] = r.y;
            row[i*4 + 2] = r.z; row[i*4 + 3] = r.w;
        }
    }

    float res[BATCH];
#pragma unroll
    for (int bb = 0; bb < BATCH; ++bb) {
        const float4* sp = (const float4*)(su + bb * EMBED);
        float acc = 0.f;
#pragma unroll
        for (int e4 = 0; e4 < 16; ++e4) {
            float4 us = sp[e4];
            acc += row[e4*4+0]*us.x + row[e4*4+1]*us.y
                 + row[e4*4+2]*us.z + row[e4*4+3]*us.w;
        }
        res[bb] = acc;
    }

    if (bf) {
        unsigned short* ob = (unsigned short*)out;
#pragma unroll
        for (int bb = 0; bb < BATCH; ++bb) {
            __hip_bfloat16 h = __float2bfloat16(res[bb]);
            ob[(size_t)bb * VOCAB + v] = *(unsigned short*)&h;
        }
    } else {
        float* of = (float*)out;
#pragma unroll
        for (int bb = 0; bb < BATCH; ++bb)
            of[(size_t)bb * VOCAB + v] = res[bb];
    }
}

extern "C" void kernel_launch(void* const* d_in, const int* in_sizes, int n_in,
                              void* d_out, int out_size, void* d_ws, size_t ws_size,
                              hipStream_t stream)
{
    const int*  stories = (const int*)d_in[0];
    const int*  queries = (const int*)d_in[1];
    const void* A       = d_in[2];
    const void* C       = d_in[3];
    const void* enc     = d_in[4];

    float* mc_ws = (float*)d_ws;                 // [6400,64]
    float* u0g   = mc_ws + NSLOT * EMBED;        // [32,64]
    float* u3g   = u0g + BATCH * EMBED;          // [32,64]

    const int nwaves  = NSLOT + BATCH;           // 6432
    const int nblocks = (nwaves + 3) / 4;        // 1608

    k_gather<<<nblocks, 256, 0, stream>>>(stories, queries, A, C, enc, mc_ws, u0g);
    k_recur2<<<BATCH, 256, 0, stream>>>(mc_ws, u0g, u3g);
    k_out<<<(VOCAB + 255) / 256, 256, 0, stream>>>(u3g, C, enc, d_out);
}